// Round 10
// baseline (476.770 us; speedup 1.0000x reference)
//
#include <hip/hip_runtime.h>
#include <hip/hip_cooperative_groups.h>

namespace cg = cooperative_groups;

// GNB dispersion — Round 17: single cooperative kernel.
// R16 (200us) analysis: kernels sum to ~125-130us; the ~70us residual is
// per-launch overhead (~14-18us x 5 launches, consistent across R3/R8/R16).
// Fuse all phases into ONE cooperative kernel with grid.sync() between:
//   P0 zero(cursor/cntrs/cn)+ballot-isCN -> P1 scatter+degree (tile steal)
//   -> P2 params -> P3 accum (unit steal, 6 blocks/CU) -> P4 reduce.
// Fallback: R16-style 5-kernel path if cooperative launch unavailable.
// ws (words): [cursor 128][cntrs 8: ocur,scur,ucur][cn n][P2 2n][isCN nwp]
//             [rep NB2*ES*1024][ovrec uint4 ocap][buckets uint2 NB2*cap]

#define B2SHIFT 10
#define B2SIZE  1024
#define MAXB    128
#define ESLICES 32
#define BLK     256
#define EPT     8
#define STILE   (BLK * EPT)      // 2048
#define AREP    4
#define FTILE   4096             // fallback scatter tile
#define FSBLK   512

__device__ __constant__ float2 GNB_RC6[87] = {
    {0.f, 0.f},
    {3.6516f, 95.99f},   {2.1843f, 40.67f},   {1.2711f, 70.21f},
    {3.3497f, 114.51f},  {2.7079f, 152.36f},  {1.8219f, 184.28f},
    {2.4667f, 482.54f},  {2.365f, 405.57f},   {1.5062f, 218.45f},
    {1.8233f, 174.81f},  {1.3974f, 181.7f},   {3.3515f, 263.02f},
    {3.0102f, 228.1f},   {3.1629f, 359.43f},  {3.2554f, 3222.12f},
    {2.9539f, 2144.49f}, {3.0368f, 2072.46f}, {2.6598f, 1357.42f},
    {4.0877f, 1406.65f}, {4.1275f, 1058.36f}, {9.7282f, 11498.73f},
    {8.5322f, 3361.33f}, {7.2344f, 2095.91f}, {5.3605f, 1049.31f},
    {3.718f, 966.27f},   {3.6408f, 1571.36f}, {3.4961f, 1183.59f},
    {3.5108f, 787.76f},  {3.0537f, 563.93f},  {3.0261f, 592.91f},
    {3.1735f, 430.82f},  {3.1773f, 812.57f},  {3.8357f, 4533.53f},
    {3.1109f, 3440.92f}, {3.2122f, 3859.82f}, {2.8263f, 2729.6f},
    {2.412f, 1864.19f},  {1.894f, 1175.73f},  {11.2061f, 32141.18f},
    {6.821f, 27655.14f}, {7.2367f, 2864.2f},  {3.901f, 3563.45f},
    {4.0857f, 3266.43f}, {4.045f, 3967.23f},  {3.4813f, 2233.82f},
    {3.0487f, 1393.49f}, {2.7795f, 1315.09f}, {2.8673f, 1311.47f},
    {3.3339f, 1460.56f}, {3.0086f, 1662.99f}, {3.9919f, 8089.97f},
    {3.4209f, 6887.05f}, {3.5649f, 8799.32f}, {3.0288f, 6136.5f},
    {2.262f, 3757.31f},  {1.3837f, 2561.18f}, {12.171f, 66580.83f},
    {0.f,0.f},{0.f,0.f},{0.f,0.f},{0.f,0.f},{0.f,0.f},{0.f,0.f},{0.f,0.f},
    {0.f,0.f},{0.f,0.f},{0.f,0.f},{0.f,0.f},{0.f,0.f},{0.f,0.f},{0.f,0.f},
    {6.0791f, 27593.76f}, {5.7661f, 15364.65f}, {3.6366f, 2734.5f},
    {4.241f, 4801.82f},   {4.1348f, 5685.94f},  {3.4213f, 2786.0f},
    {3.2486f, 2699.79f},  {2.9588f, 2282.6f},   {2.9381f, 2476.79f},
    {2.7711f, 2988.7f},   {2.5816f, 2506.63f},  {3.785f, 8916.84f},
    {3.5381f, 8694.22f},  {3.6985f, 11821.61f}, {3.0551f, 8410.64f},
};

__device__ __forceinline__ float gnb_energy_eval(float2 ps, float2 pr, float rlen) {
    float env;
    if (rlen < 8.0f) {
        env = 1.0f;
    } else {
        float x = (rlen - 8.0f) * 0.5f;          // kept edges guarantee x < 1
        float x2 = x * x;
        float x6 = x2 * x2 * x2;
        env = 1.0f - 28.0f * x6 + 48.0f * x6 * x - 21.0f * x6 * x2;
    }
    float sR  = ps.y * pr.y;                     // sqrt(R_ij)
    float C6  = ps.x * pr.x;                     // sqrt(C6_s*C6_r)
    float Rij = sR * sR;
    float R3  = Rij * Rij * Rij;
    float R6  = R3 * R3;
    float r0  = 0.4f * sR + 4.0f;
    float t   = r0 / rlen;
    float t2 = t * t, t4 = t2 * t2, t8 = t4 * t4;
    float t14 = t8 * t4 * t2;
    float fd = 1.0f / (1.0f + 6.0f * t14);
    float rl2 = rlen * rlen;
    float r6 = rl2 * rl2 * rl2;
    return -0.5f * C6 / (R6 + r6) * fd * env;
}

__device__ __forceinline__ void params_one(const int* Z, const int* cn,
                                           float2* P2, int i) {
    int z = Z[i];
    float Rp, C6;
    if (z == 6) {
        if (cn[i] <= 3) { Rp = 2.2348f; C6 = 429.69f; }
        else            { Rp = 1.8219f; C6 = 184.28f; }
    } else if (z == 7) {
        if (cn[i] <= 2) { Rp = 2.6454f; C6 = 720.18f; }
        else            { Rp = 2.4667f; C6 = 482.54f; }
    } else {
        float2 rc = GNB_RC6[z];
        Rp = rc.x; C6 = rc.y;
    }
    P2[i] = make_float2(sqrtf(C6), sqrtf(sqrtf(Rp)));
}

// ---------------- fused cooperative kernel ----------------
__global__ void __launch_bounds__(BLK)
gnb_fused(const int* __restrict__ Z, const int* __restrict__ send,
          const int* __restrict__ recv, const float* __restrict__ len,
          float* __restrict__ out,
          unsigned* __restrict__ cursor, unsigned* __restrict__ cntrs,
          int* __restrict__ cn, float2* __restrict__ P2,
          unsigned* __restrict__ isCN, float* __restrict__ rep,
          uint4* __restrict__ ovrec, uint2* __restrict__ buckets,
          int n_nodes, int n_edges, unsigned cap, unsigned ocap,
          int nw, int NB2, int ntiles, int nunits) {
    cg::grid_group grid = cg::this_grid();
    __shared__ union {
        struct { unsigned hist[MAXB]; unsigned gbase[MAXB]; } s;
        struct { float acc[AREP][B2SIZE + 8]; float2 p2loc[B2SIZE]; } a;
    } sh;
    __shared__ unsigned steal;
    const int tid = threadIdx.x;
    const int gtid = blockIdx.x * BLK + tid;
    const int gstride = gridDim.x * BLK;
    unsigned* ocur = cntrs + 0;
    unsigned* scur = cntrs + 1;
    unsigned* ucur = cntrs + 2;

    // ---- P0: zero [cursor|cntrs|cn] + ballot-built isCN ----
    {
        int zwords = MAXB + 8 + n_nodes;
        int zq = zwords >> 2;
        int4* zp4 = (int4*)cursor;
        int4 z4 = make_int4(0, 0, 0, 0);
        for (int i = gtid; i < zq; i += gstride) zp4[i] = z4;
        for (int i = (zq << 2) + gtid; i < zwords; i += gstride)
            ((int*)cursor)[i] = 0;
        int nal = (n_nodes + 63) & ~63;
        for (int i = gtid; i < nal; i += gstride) {
            bool pred = false;
            if (i < n_nodes) { int z = Z[i]; pred = (z == 6) | (z == 7); }
            unsigned long long m = __ballot(pred);
            if ((tid & 63) == 0) {
                int w = i >> 5;
                if (w < nw)     isCN[w]     = (unsigned)m;
                if (w + 1 < nw) isCN[w + 1] = (unsigned)(m >> 32);
            }
        }
    }
    grid.sync();

    // ---- P1: scatter + fused degree (work-steal over tiles) ----
    for (;;) {
        if (tid == 0) steal = atomicAdd(scur, 1u);
        __syncthreads();
        unsigned t = steal;
        if (t >= (unsigned)ntiles) break;
        if (tid < MAXB) sh.s.hist[tid] = 0;
        __syncthreads();

        const int e0 = (int)t * STILE;
        unsigned ss[EPT]; unsigned rr[EPT]; float ll[EPT];
        const bool full = (e0 + STILE <= n_edges);
        if (full) {
            int4   sv0 = *(const int4*)(send + e0 + tid * 4);
            int4   rv0 = *(const int4*)(recv + e0 + tid * 4);
            float4 lv0 = *(const float4*)(len + e0 + tid * 4);
            int4   sv1 = *(const int4*)(send + e0 + 1024 + tid * 4);
            int4   rv1 = *(const int4*)(recv + e0 + 1024 + tid * 4);
            float4 lv1 = *(const float4*)(len + e0 + 1024 + tid * 4);
            ss[0]=(unsigned)sv0.x; ss[1]=(unsigned)sv0.y; ss[2]=(unsigned)sv0.z; ss[3]=(unsigned)sv0.w;
            ss[4]=(unsigned)sv1.x; ss[5]=(unsigned)sv1.y; ss[6]=(unsigned)sv1.z; ss[7]=(unsigned)sv1.w;
            rr[0]=(unsigned)rv0.x; rr[1]=(unsigned)rv0.y; rr[2]=(unsigned)rv0.z; rr[3]=(unsigned)rv0.w;
            rr[4]=(unsigned)rv1.x; rr[5]=(unsigned)rv1.y; rr[6]=(unsigned)rv1.z; rr[7]=(unsigned)rv1.w;
            ll[0]=lv0.x; ll[1]=lv0.y; ll[2]=lv0.z; ll[3]=lv0.w;
            ll[4]=lv1.x; ll[5]=lv1.y; ll[6]=lv1.z; ll[7]=lv1.w;
        } else {
            #pragma unroll
            for (int i = 0; i < EPT; ++i) {
                int e = e0 + ((i >> 2) * 1024) + tid * 4 + (i & 3);
                bool ok = (e < n_edges);
                ss[i] = ok ? (unsigned)send[e] : 0u;
                rr[i] = ok ? (unsigned)recv[e] : 0u;
                ll[i] = ok ? len[e] : 1.0e9f;
            }
        }

        #pragma unroll
        for (int i = 0; i < EPT; ++i) {
            if (ll[i] < 1.0e8f && ((isCN[rr[i] >> 5] >> (rr[i] & 31)) & 1u))
                atomicAdd(&cn[rr[i]], 1);
        }

        unsigned bk[EPT];
        #pragma unroll
        for (int i = 0; i < EPT; ++i) {
            if (ll[i] < 10.0f) {
                unsigned b   = rr[i] >> B2SHIFT;
                unsigned off = atomicAdd(&sh.s.hist[b], 1u);
                bk[i] = b | (off << 7);
            } else {
                bk[i] = 0x80000000u;
            }
        }
        __syncthreads();

        if (tid < MAXB) {
            unsigned c = sh.s.hist[tid];
            sh.s.gbase[tid] = c ? atomicAdd(&cursor[tid], c) : 0u;
        }
        __syncthreads();

        #pragma unroll
        for (int i = 0; i < EPT; ++i) {
            unsigned bo = bk[i];
            if (!(bo & 0x80000000u)) {
                unsigned b = bo & (MAXB - 1);
                unsigned g = sh.s.gbase[b] + (bo >> 7);
                unsigned x = ss[i] | ((rr[i] & (B2SIZE - 1)) << 17);
                if (g < cap) {
                    buckets[(size_t)b * cap + g] =
                        make_uint2(x, __float_as_uint(ll[i]));
                } else {
                    unsigned o = atomicAdd(ocur, 1u);
                    if (o < ocap)
                        ovrec[o] = make_uint4(rr[i], ss[i],
                                              __float_as_uint(ll[i]), 0u);
                }
            }
        }
        // loop-top __syncthreads orders gbase reads vs next hist zero
    }
    grid.sync();

    // ---- P2: params ----
    for (int i = gtid; i < n_nodes; i += gstride) params_one(Z, cn, P2, i);
    grid.sync();

    // ---- P3: accum (work-steal over bucket x slice units) ----
    for (;;) {
        if (tid == 0) steal = atomicAdd(ucur, 1u);
        __syncthreads();
        unsigned u = steal;
        if (u >= (unsigned)nunits) break;
        const int b  = (int)(u >> 5);            // ESLICES == 32
        const int sl = (int)(u & (ESLICES - 1));
        const int rp = (tid >> 6) & (AREP - 1);

        float* accf = &sh.a.acc[0][0];
        for (int i = tid; i < AREP * (B2SIZE + 8); i += BLK) accf[i] = 0.0f;
        for (int i = tid; i < B2SIZE; i += BLK) {
            int node = (b << B2SHIFT) + i;
            sh.a.p2loc[i] = (node < n_nodes) ? P2[node] : make_float2(0.f, 0.f);
        }
        __syncthreads();

        unsigned count = cursor[b];
        if (count > cap) count = cap;
        unsigned seg = (((count + ESLICES - 1) / ESLICES) + 3u) & ~3u;
        unsigned st  = (unsigned)sl * seg; if (st > count) st = count;
        unsigned en  = st + seg; if (en > count) en = count;

        const uint2* src = buckets + (size_t)b * cap;
        for (unsigned i = st + tid * 4; i < en; i += BLK * 4) {
            if (i + 4 <= en) {
                uint4 q0 = *(const uint4*)(src + i);
                uint4 q1 = *(const uint4*)(src + i + 2);
                unsigned sx[4] = {q0.x, q0.z, q1.x, q1.z};
                unsigned lb[4] = {q0.y, q0.w, q1.y, q1.w};
                float2 ps[4];
                #pragma unroll
                for (int j = 0; j < 4; ++j) ps[j] = P2[sx[j] & 0x1FFFFu];
                #pragma unroll
                for (int j = 0; j < 4; ++j) {
                    unsigned rlow = (sx[j] >> 17) & (B2SIZE - 1);
                    float e = gnb_energy_eval(ps[j], sh.a.p2loc[rlow],
                                              __uint_as_float(lb[j]));
                    atomicAdd(&sh.a.acc[rp][rlow], e);
                }
            } else {
                for (unsigned q = i; q < en; ++q) {
                    uint2 rec = src[q];
                    unsigned rlow = (rec.x >> 17) & (B2SIZE - 1);
                    float e = gnb_energy_eval(P2[rec.x & 0x1FFFFu],
                                              sh.a.p2loc[rlow],
                                              __uint_as_float(rec.y));
                    atomicAdd(&sh.a.acc[rp][rlow], e);
                }
            }
        }

        if (sl == 0) {                           // overflow fold (usually empty)
            unsigned n = *ocur; if (n > ocap) n = ocap;
            for (unsigned i = tid; i < n; i += BLK) {
                uint4 rc = ovrec[i];
                if ((rc.x >> B2SHIFT) == (unsigned)b) {
                    float e = gnb_energy_eval(P2[rc.y],
                                              sh.a.p2loc[rc.x & (B2SIZE - 1)],
                                              __uint_as_float(rc.z));
                    atomicAdd(&sh.a.acc[rp][rc.x & (B2SIZE - 1)], e);
                }
            }
        }
        __syncthreads();

        float* dst = rep + (size_t)u * B2SIZE;
        for (int i = tid; i < B2SIZE; i += BLK)
            dst[i] = (sh.a.acc[0][i] + sh.a.acc[1][i]) +
                     (sh.a.acc[2][i] + sh.a.acc[3][i]);
        // loop-top __syncthreads orders acc reads vs next zero
    }
    grid.sync();

    // ---- P4: reduce ----
    for (int i = gtid; i < n_nodes; i += gstride) {
        int b = i >> B2SHIFT;
        int j = i & (B2SIZE - 1);
        const float* src = rep + ((size_t)b * ESLICES) * B2SIZE + j;
        float s = 0.0f;
        #pragma unroll
        for (int k = 0; k < ESLICES; ++k) s += src[(size_t)k * B2SIZE];
        out[i] = s;
    }
}

// ---------------- fallback path (R16 structure, 5 launches) ----------------
__global__ void fb_init(const int* __restrict__ Z, unsigned* __restrict__ isCN,
                        int nw, int n_nodes, int4* __restrict__ zp4, int zq,
                        int* __restrict__ zp, int zwords) {
    int stride = gridDim.x * blockDim.x;
    int t0 = blockIdx.x * blockDim.x + threadIdx.x;
    int4 z4 = make_int4(0, 0, 0, 0);
    for (int i = t0; i < zq; i += stride) zp4[i] = z4;
    for (int i = zq * 4 + t0; i < zwords; i += stride) zp[i] = 0;
    for (int w = t0; w < nw; w += stride) {
        unsigned m = 0;
        int base = w << 5;
        int lim = n_nodes - base; if (lim > 32) lim = 32;
        for (int k = 0; k < lim; ++k) {
            int z = Z[base + k];
            if (z == 6 || z == 7) m |= (1u << k);
        }
        isCN[w] = m;
    }
}

__global__ void fb_params(const int* __restrict__ Z, const int* __restrict__ cn,
                          float2* __restrict__ P2, int n_nodes) {
    int i = blockIdx.x * blockDim.x + threadIdx.x;
    if (i < n_nodes) params_one(Z, cn, P2, i);
}

__global__ void __launch_bounds__(FSBLK)
fb_scatter(const int* __restrict__ send, const int* __restrict__ recv,
           const float* __restrict__ len, const unsigned* __restrict__ isCN,
           int* __restrict__ cn,
           uint2* __restrict__ buckets, unsigned* __restrict__ cursor,
           uint4* __restrict__ ovrec, unsigned* __restrict__ ocur,
           int n_edges, unsigned cap, unsigned ocap) {
    __shared__ unsigned hist[MAXB];
    __shared__ unsigned gbase[MAXB];
    const int tid = threadIdx.x;
    const int e0  = blockIdx.x * FTILE;
    if (tid < MAXB) hist[tid] = 0;
    __syncthreads();
    unsigned ss[8]; unsigned rr[8]; float ll[8];
    const bool full = (e0 + FTILE <= n_edges);
    if (full) {
        int4   sv0 = *(const int4*)(send + e0 + tid * 4);
        int4   rv0 = *(const int4*)(recv + e0 + tid * 4);
        float4 lv0 = *(const float4*)(len + e0 + tid * 4);
        int4   sv1 = *(const int4*)(send + e0 + 2048 + tid * 4);
        int4   rv1 = *(const int4*)(recv + e0 + 2048 + tid * 4);
        float4 lv1 = *(const float4*)(len + e0 + 2048 + tid * 4);
        ss[0]=(unsigned)sv0.x; ss[1]=(unsigned)sv0.y; ss[2]=(unsigned)sv0.z; ss[3]=(unsigned)sv0.w;
        ss[4]=(unsigned)sv1.x; ss[5]=(unsigned)sv1.y; ss[6]=(unsigned)sv1.z; ss[7]=(unsigned)sv1.w;
        rr[0]=(unsigned)rv0.x; rr[1]=(unsigned)rv0.y; rr[2]=(unsigned)rv0.z; rr[3]=(unsigned)rv0.w;
        rr[4]=(unsigned)rv1.x; rr[5]=(unsigned)rv1.y; rr[6]=(unsigned)rv1.z; rr[7]=(unsigned)rv1.w;
        ll[0]=lv0.x; ll[1]=lv0.y; ll[2]=lv0.z; ll[3]=lv0.w;
        ll[4]=lv1.x; ll[5]=lv1.y; ll[6]=lv1.z; ll[7]=lv1.w;
    } else {
        #pragma unroll
        for (int i = 0; i < 8; ++i) {
            int e = e0 + ((i >> 2) * 2048) + tid * 4 + (i & 3);
            bool ok = (e < n_edges);
            ss[i] = ok ? (unsigned)send[e] : 0u;
            rr[i] = ok ? (unsigned)recv[e] : 0u;
            ll[i] = ok ? len[e] : 1.0e9f;
        }
    }
    #pragma unroll
    for (int i = 0; i < 8; ++i) {
        if (ll[i] < 1.0e8f && ((isCN[rr[i] >> 5] >> (rr[i] & 31)) & 1u))
            atomicAdd(&cn[rr[i]], 1);
    }
    unsigned bk[8];
    #pragma unroll
    for (int i = 0; i < 8; ++i) {
        if (ll[i] < 10.0f) {
            unsigned b   = rr[i] >> B2SHIFT;
            unsigned off = atomicAdd(&hist[b], 1u);
            bk[i] = b | (off << 7);
        } else {
            bk[i] = 0x80000000u;
        }
    }
    __syncthreads();
    if (tid < MAXB) {
        unsigned c = hist[tid];
        gbase[tid] = c ? atomicAdd(&cursor[tid], c) : 0u;
    }
    __syncthreads();
    #pragma unroll
    for (int i = 0; i < 8; ++i) {
        unsigned bo = bk[i];
        if (!(bo & 0x80000000u)) {
            unsigned b = bo & (MAXB - 1);
            unsigned g = gbase[b] + (bo >> 7);
            unsigned x = ss[i] | ((rr[i] & (B2SIZE - 1)) << 17);
            if (g < cap) {
                buckets[(size_t)b * cap + g] = make_uint2(x, __float_as_uint(ll[i]));
            } else {
                unsigned o = atomicAdd(ocur, 1u);
                if (o < ocap)
                    ovrec[o] = make_uint4(rr[i], ss[i], __float_as_uint(ll[i]), 0u);
            }
        }
    }
}

__global__ void __launch_bounds__(BLK)
fb_accum(const uint2* __restrict__ buckets, const unsigned* __restrict__ cursor,
         const uint4* __restrict__ ovrec, const unsigned* __restrict__ ocur,
         const float2* __restrict__ P2, float* __restrict__ rep,
         unsigned cap, unsigned ocap, int n_nodes) {
    __shared__ float  acc[AREP][B2SIZE + 8];
    __shared__ float2 p2loc[B2SIZE];
    const int b   = blockIdx.x / ESLICES;
    const int sl  = blockIdx.x % ESLICES;
    const int tid = threadIdx.x;
    const int rp  = (tid >> 6) & (AREP - 1);
    for (int i = tid; i < AREP * (B2SIZE + 8); i += BLK) acc[0][i] = 0.0f;
    for (int i = tid; i < B2SIZE; i += BLK) {
        int node = (b << B2SHIFT) + i;
        p2loc[i] = (node < n_nodes) ? P2[node] : make_float2(0.f, 0.f);
    }
    __syncthreads();
    unsigned count = cursor[b];
    if (count > cap) count = cap;
    unsigned seg = (((count + ESLICES - 1) / ESLICES) + 3u) & ~3u;
    unsigned st  = (unsigned)sl * seg; if (st > count) st = count;
    unsigned en  = st + seg; if (en > count) en = count;
    const uint2* src = buckets + (size_t)b * cap;
    for (unsigned i = st + tid * 4; i < en; i += BLK * 4) {
        if (i + 4 <= en) {
            uint4 q0 = *(const uint4*)(src + i);
            uint4 q1 = *(const uint4*)(src + i + 2);
            unsigned sx[4] = {q0.x, q0.z, q1.x, q1.z};
            unsigned lb[4] = {q0.y, q0.w, q1.y, q1.w};
            float2 ps[4];
            #pragma unroll
            for (int j = 0; j < 4; ++j) ps[j] = P2[sx[j] & 0x1FFFFu];
            #pragma unroll
            for (int j = 0; j < 4; ++j) {
                unsigned rlow = (sx[j] >> 17) & (B2SIZE - 1);
                float e = gnb_energy_eval(ps[j], p2loc[rlow], __uint_as_float(lb[j]));
                atomicAdd(&acc[rp][rlow], e);
            }
        } else {
            for (unsigned q = i; q < en; ++q) {
                uint2 rec = src[q];
                unsigned rlow = (rec.x >> 17) & (B2SIZE - 1);
                float e = gnb_energy_eval(P2[rec.x & 0x1FFFFu], p2loc[rlow],
                                          __uint_as_float(rec.y));
                atomicAdd(&acc[rp][rlow], e);
            }
        }
    }
    if (sl == 0) {
        unsigned n = *ocur; if (n > ocap) n = ocap;
        for (unsigned i = tid; i < n; i += BLK) {
            uint4 rc = ovrec[i];
            if ((rc.x >> B2SHIFT) == (unsigned)b) {
                float e = gnb_energy_eval(P2[rc.y], p2loc[rc.x & (B2SIZE - 1)],
                                          __uint_as_float(rc.z));
                atomicAdd(&acc[rp][rc.x & (B2SIZE - 1)], e);
            }
        }
    }
    __syncthreads();
    float* dst = rep + (size_t)blockIdx.x * B2SIZE;
    for (int i = tid; i < B2SIZE; i += BLK)
        dst[i] = (acc[0][i] + acc[1][i]) + (acc[2][i] + acc[3][i]);
}

__global__ void fb_reduce(const float* __restrict__ rep, float* __restrict__ out,
                          int n_nodes) {
    int i = blockIdx.x * blockDim.x + threadIdx.x;
    if (i >= n_nodes) return;
    int b = i >> B2SHIFT;
    int j = i & (B2SIZE - 1);
    const float* src = rep + ((size_t)b * ESLICES) * B2SIZE + j;
    float sum = 0.0f;
    #pragma unroll
    for (int s = 0; s < ESLICES; ++s) sum += src[(size_t)s * B2SIZE];
    out[i] = sum;
}

extern "C" void kernel_launch(void* const* d_in, const int* in_sizes, int n_in,
                              void* d_out, int out_size, void* d_ws, size_t ws_size,
                              hipStream_t stream) {
    const int*   Z    = (const int*)d_in[0];
    const int*   eidx = (const int*)d_in[1];
    const float* len  = (const float*)d_in[2];
    float*       out  = (float*)d_out;

    const int n_nodes = in_sizes[0];
    const int n_edges = in_sizes[2];
    const int* send = eidx;
    const int* recv = eidx + n_edges;

    const int NB2 = (n_nodes + B2SIZE - 1) >> B2SHIFT;   // 98 for n=100000
    const int nw  = (n_nodes + 31) >> 5;
    const int nwp = (nw + 7) & ~7;

    // ws layout (words): [cursor 128][cntrs 8][cn n][P2 2n][isCN nwp][rep][tail]
    char* ws = (char*)d_ws;
    unsigned* cursor = (unsigned*)ws;                                          // 128
    unsigned* cntrs  = (unsigned*)(ws + MAXB * 4);                             // 8
    int*      cn     = (int*)(ws + (MAXB + 8) * 4);                            // n
    float2*   P2     = (float2*)(ws + ((size_t)n_nodes + MAXB + 8) * 4);       // 2n
    unsigned* isCN   = (unsigned*)(ws + ((size_t)3 * n_nodes + MAXB + 8) * 4); // nwp
    float*    rep    = (float*)((char*)isCN + (size_t)nwp * 4);
    size_t rep_w     = (size_t)NB2 * ESLICES * B2SIZE;
    char*     tail   = (char*)rep + rep_w * 4;

    size_t fixed_words = (size_t)3 * n_nodes + MAXB + 8 + nwp + rep_w;
    size_t total_words = ws_size / 4;
    size_t avail = total_words > fixed_words ? total_words - fixed_words : 0;
    size_t ovw = avail / 64;                      // ~1.5% to overflow queue
    unsigned ocap = (unsigned)(ovw / 4);          // uint4 records
    size_t capw = (avail - ovw) / (size_t)NB2;    // words per bucket
    long cap = (long)((capw / 2) & ~(size_t)3);   // uint2 records, 4-rec aligned
    if (cap > n_edges) cap = (n_edges + 3) & ~3;
    if (cap < 0) cap = 0;
    uint4* ovrec   = (uint4*)tail;
    uint2* buckets = (uint2*)(tail + (size_t)ocap * 16);

    int ntiles = (n_edges + STILE - 1) / STILE;
    int nunits = NB2 * ESLICES;
    unsigned capu = (unsigned)cap;

    // cooperative grid size (query once)
    static int s_grid = -2;
    if (s_grid == -2) {
        s_grid = -1;
        hipDeviceProp_t prop;
        if (hipGetDeviceProperties(&prop, 0) == hipSuccess) {
            int mab = 0;
            if (hipOccupancyMaxActiveBlocksPerMultiprocessor(
                    &mab, gnb_fused, BLK, 0) == hipSuccess && mab > 0)
                s_grid = prop.multiProcessorCount * mab;
        }
    }

    bool coop_ok = false;
    if (s_grid > 0) {
        int nn = n_nodes, ne = n_edges, nwv = nw, nb2 = NB2, nt = ntiles,
            nu = nunits;
        void* args[] = {
            (void*)&Z, (void*)&send, (void*)&recv, (void*)&len, (void*)&out,
            (void*)&cursor, (void*)&cntrs, (void*)&cn, (void*)&P2,
            (void*)&isCN, (void*)&rep, (void*)&ovrec, (void*)&buckets,
            (void*)&nn, (void*)&ne, (void*)&capu, (void*)&ocap,
            (void*)&nwv, (void*)&nb2, (void*)&nt, (void*)&nu };
        coop_ok = hipLaunchCooperativeKernel((const void*)gnb_fused,
                                             dim3(s_grid), dim3(BLK),
                                             args, 0, stream) == hipSuccess;
    }

    if (!coop_ok) {                               // 5-launch fallback (R16)
        const int B = 256;
        int node_blocks = (n_nodes + B - 1) / B;
        int scat_blocks = (n_edges + FTILE - 1) / FTILE;
        int zero_words  = n_nodes + MAXB + 8;
        int zq = zero_words / 4;
        fb_init<<<256, B, 0, stream>>>(Z, isCN, nw, n_nodes, (int4*)ws, zq,
                                       (int*)ws, zero_words);
        fb_scatter<<<scat_blocks, FSBLK, 0, stream>>>(send, recv, len, isCN, cn,
                                                      buckets, cursor, ovrec,
                                                      cntrs, n_edges, capu, ocap);
        fb_params<<<node_blocks, B, 0, stream>>>(Z, cn, P2, n_nodes);
        fb_accum<<<nunits, BLK, 0, stream>>>(buckets, cursor, ovrec, cntrs,
                                             P2, rep, capu, ocap, n_nodes);
        fb_reduce<<<node_blocks, B, 0, stream>>>(rep, out, n_nodes);
    }
}

// Round 11
// 384.960 us; speedup vs baseline: 1.2385x; 1.2385x over previous
//
#include <hip/hip_runtime.h>

// GNB dispersion — Round 18: R16 base + last-block reduce fold + high-TLP accum.
// R17 refuted grid.sync fusion: ~150us per sync on 8-XCD MI355X (732us fused vs
// ~130us of work). Launch overhead (~13-16us x launches) is real, so cut a
// launch the cheap way: accum's 16th slice-block per bucket does the reduce
// (threadfence + done-counter, G16 idiom). Accum TLP doubled: AREP 4->2,
// ESLICES 8->16 -> LDS 16.5KB, ~6 blocks/CU resident, ~24 waves/CU over the
// 6M P2[s] gathers. Scatter/params/init identical to R16 (scatter=62us proven).
//   init -> scatter(+degree) -> params -> accum(+reduce)
// Record: uint2{ s | rlow<<17, len_bits }.
// ws (words): [cursor 128][done 128][cntrs 8][cn cnw][P2 2n][isCN nwp]
//             [rep NB2*ES*1024][ovrec uint4 ocap][buckets uint2 NB2*cap]

#define B2SHIFT 10
#define B2SIZE  1024
#define TILE    4096
#define SBLK    512
#define ESLICES 16
#define MAXB    128
#define AREP    2
#define BLK     256

__device__ __constant__ float2 GNB_RC6[87] = {
    {0.f, 0.f},
    {3.6516f, 95.99f},   {2.1843f, 40.67f},   {1.2711f, 70.21f},
    {3.3497f, 114.51f},  {2.7079f, 152.36f},  {1.8219f, 184.28f},
    {2.4667f, 482.54f},  {2.365f, 405.57f},   {1.5062f, 218.45f},
    {1.8233f, 174.81f},  {1.3974f, 181.7f},   {3.3515f, 263.02f},
    {3.0102f, 228.1f},   {3.1629f, 359.43f},  {3.2554f, 3222.12f},
    {2.9539f, 2144.49f}, {3.0368f, 2072.46f}, {2.6598f, 1357.42f},
    {4.0877f, 1406.65f}, {4.1275f, 1058.36f}, {9.7282f, 11498.73f},
    {8.5322f, 3361.33f}, {7.2344f, 2095.91f}, {5.3605f, 1049.31f},
    {3.718f, 966.27f},   {3.6408f, 1571.36f}, {3.4961f, 1183.59f},
    {3.5108f, 787.76f},  {3.0537f, 563.93f},  {3.0261f, 592.91f},
    {3.1735f, 430.82f},  {3.1773f, 812.57f},  {3.8357f, 4533.53f},
    {3.1109f, 3440.92f}, {3.2122f, 3859.82f}, {2.8263f, 2729.6f},
    {2.412f, 1864.19f},  {1.894f, 1175.73f},  {11.2061f, 32141.18f},
    {6.821f, 27655.14f}, {7.2367f, 2864.2f},  {3.901f, 3563.45f},
    {4.0857f, 3266.43f}, {4.045f, 3967.23f},  {3.4813f, 2233.82f},
    {3.0487f, 1393.49f}, {2.7795f, 1315.09f}, {2.8673f, 1311.47f},
    {3.3339f, 1460.56f}, {3.0086f, 1662.99f}, {3.9919f, 8089.97f},
    {3.4209f, 6887.05f}, {3.5649f, 8799.32f}, {3.0288f, 6136.5f},
    {2.262f, 3757.31f},  {1.3837f, 2561.18f}, {12.171f, 66580.83f},
    {0.f,0.f},{0.f,0.f},{0.f,0.f},{0.f,0.f},{0.f,0.f},{0.f,0.f},{0.f,0.f},
    {0.f,0.f},{0.f,0.f},{0.f,0.f},{0.f,0.f},{0.f,0.f},{0.f,0.f},{0.f,0.f},
    {6.0791f, 27593.76f}, {5.7661f, 15364.65f}, {3.6366f, 2734.5f},
    {4.241f, 4801.82f},   {4.1348f, 5685.94f},  {3.4213f, 2786.0f},
    {3.2486f, 2699.79f},  {2.9588f, 2282.6f},   {2.9381f, 2476.79f},
    {2.7711f, 2988.7f},   {2.5816f, 2506.63f},  {3.785f, 8916.84f},
    {3.5381f, 8694.22f},  {3.6985f, 11821.61f}, {3.0551f, 8410.64f},
};

// Zero [cursor|done|cntrs|cn] (contiguous at ws start) + build isCN bitmask.
__global__ void gnb_init(const int* __restrict__ Z, unsigned* __restrict__ isCN,
                         int nw, int n_nodes, int4* __restrict__ zp4, int zq,
                         int* __restrict__ zp, int zwords) {
    int stride = gridDim.x * blockDim.x;
    int t0 = blockIdx.x * blockDim.x + threadIdx.x;
    int4 z4 = make_int4(0, 0, 0, 0);
    for (int i = t0; i < zq; i += stride) zp4[i] = z4;
    for (int i = zq * 4 + t0; i < zwords; i += stride) zp[i] = 0;
    for (int w = t0; w < nw; w += stride) {
        unsigned m = 0;
        int base = w << 5;
        int lim = n_nodes - base; if (lim > 32) lim = 32;
        for (int k = 0; k < lim; ++k) {
            int z = Z[base + k];
            if (z == 6 || z == 7) m |= (1u << k);
        }
        isCN[w] = m;
    }
}

__global__ void gnb_params(const int* __restrict__ Z, const int* __restrict__ cn,
                           float2* __restrict__ P2, int n_nodes) {
    int i = blockIdx.x * blockDim.x + threadIdx.x;
    if (i >= n_nodes) return;
    int z = Z[i];
    float Rp, C6;
    if (z == 6) {
        if (cn[i] <= 3) { Rp = 2.2348f; C6 = 429.69f; }
        else            { Rp = 1.8219f; C6 = 184.28f; }
    } else if (z == 7) {
        if (cn[i] <= 2) { Rp = 2.6454f; C6 = 720.18f; }
        else            { Rp = 2.4667f; C6 = 482.54f; }
    } else {
        float2 rc = GNB_RC6[z];
        Rp = rc.x; C6 = rc.y;
    }
    P2[i] = make_float2(sqrtf(C6), sqrtf(sqrtf(Rp)));
}

__device__ __forceinline__ float gnb_energy_eval(float2 ps, float2 pr, float rlen) {
    float env;
    if (rlen < 8.0f) {
        env = 1.0f;
    } else {
        float x = (rlen - 8.0f) * 0.5f;          // kept edges guarantee x < 1
        float x2 = x * x;
        float x6 = x2 * x2 * x2;
        env = 1.0f - 28.0f * x6 + 48.0f * x6 * x - 21.0f * x6 * x2;
    }
    float sR  = ps.y * pr.y;                     // sqrt(R_ij)
    float C6  = ps.x * pr.x;                     // sqrt(C6_s*C6_r)
    float Rij = sR * sR;
    float R3  = Rij * Rij * Rij;
    float R6  = R3 * R3;
    float r0  = 0.4f * sR + 4.0f;
    float t   = r0 / rlen;
    float t2 = t * t, t4 = t2 * t2, t8 = t4 * t4;
    float t14 = t8 * t4 * t2;
    float fd = 1.0f / (1.0f + 6.0f * t14);
    float rl2 = rlen * rlen;
    float r6 = rl2 * rl2 * rl2;
    return -0.5f * C6 / (R6 + r6) * fd * env;
}

// Gather-free scatter (+fused degree): identical to R16 (62us proven).
__global__ void __launch_bounds__(SBLK)
gnb_scatter(const int* __restrict__ send, const int* __restrict__ recv,
            const float* __restrict__ len, const unsigned* __restrict__ isCN,
            int* __restrict__ cn,
            uint2* __restrict__ buckets, unsigned* __restrict__ cursor,
            uint4* __restrict__ ovrec, unsigned* __restrict__ ocur,
            int n_edges, unsigned cap, unsigned ocap) {
    __shared__ unsigned hist[MAXB];
    __shared__ unsigned gbase[MAXB];
    const int tid = threadIdx.x;
    const int e0  = blockIdx.x * TILE;

    if (tid < MAXB) hist[tid] = 0;
    __syncthreads();

    unsigned ss[8]; unsigned rr[8]; float ll[8];
    const bool full = (e0 + TILE <= n_edges);
    if (full) {
        int4   sv0 = *(const int4*)(send + e0 + tid * 4);
        int4   rv0 = *(const int4*)(recv + e0 + tid * 4);
        float4 lv0 = *(const float4*)(len + e0 + tid * 4);
        int4   sv1 = *(const int4*)(send + e0 + 2048 + tid * 4);
        int4   rv1 = *(const int4*)(recv + e0 + 2048 + tid * 4);
        float4 lv1 = *(const float4*)(len + e0 + 2048 + tid * 4);
        ss[0]=(unsigned)sv0.x; ss[1]=(unsigned)sv0.y; ss[2]=(unsigned)sv0.z; ss[3]=(unsigned)sv0.w;
        ss[4]=(unsigned)sv1.x; ss[5]=(unsigned)sv1.y; ss[6]=(unsigned)sv1.z; ss[7]=(unsigned)sv1.w;
        rr[0]=(unsigned)rv0.x; rr[1]=(unsigned)rv0.y; rr[2]=(unsigned)rv0.z; rr[3]=(unsigned)rv0.w;
        rr[4]=(unsigned)rv1.x; rr[5]=(unsigned)rv1.y; rr[6]=(unsigned)rv1.z; rr[7]=(unsigned)rv1.w;
        ll[0]=lv0.x; ll[1]=lv0.y; ll[2]=lv0.z; ll[3]=lv0.w;
        ll[4]=lv1.x; ll[5]=lv1.y; ll[6]=lv1.z; ll[7]=lv1.w;
    } else {
        #pragma unroll
        for (int i = 0; i < 8; ++i) {
            int e = e0 + ((i >> 2) * 2048) + tid * 4 + (i & 3);
            bool ok = (e < n_edges);
            ss[i] = ok ? (unsigned)send[e] : 0u;
            rr[i] = ok ? (unsigned)recv[e] : 0u;
            ll[i] = ok ? len[e] : 1.0e9f;
        }
    }

    // fused degree: ALL edges, isCN-filtered (~2.3% fire), fire-and-forget
    #pragma unroll
    for (int i = 0; i < 8; ++i) {
        if (ll[i] < 1.0e8f && ((isCN[rr[i] >> 5] >> (rr[i] & 31)) & 1u))
            atomicAdd(&cn[rr[i]], 1);
    }

    unsigned bk[8];
    #pragma unroll
    for (int i = 0; i < 8; ++i) {
        if (ll[i] < 10.0f) {
            unsigned b   = rr[i] >> B2SHIFT;
            unsigned off = atomicAdd(&hist[b], 1u);
            bk[i] = b | (off << 7);
        } else {
            bk[i] = 0x80000000u;
        }
    }
    __syncthreads();

    if (tid < MAXB) {
        unsigned c = hist[tid];
        gbase[tid] = c ? atomicAdd(&cursor[tid], c) : 0u;
    }
    __syncthreads();

    #pragma unroll
    for (int i = 0; i < 8; ++i) {
        unsigned bo = bk[i];
        if (!(bo & 0x80000000u)) {
            unsigned b = bo & (MAXB - 1);
            unsigned g = gbase[b] + (bo >> 7);
            unsigned x = ss[i] | ((rr[i] & (B2SIZE - 1)) << 17);
            if (g < cap) {
                buckets[(size_t)b * cap + g] = make_uint2(x, __float_as_uint(ll[i]));
            } else {
                unsigned o = atomicAdd(ocur, 1u);
                if (o < ocap)
                    ovrec[o] = make_uint4(rr[i], ss[i], __float_as_uint(ll[i]), 0u);
            }
        }
    }
}

// Accum (+folded reduce): stage bucket P2 in LDS, stream records, gather P2[s],
// eval, LDS add (2 replicas). Last slice-block per bucket reduces rep -> out.
__global__ void __launch_bounds__(BLK)
gnb_accum(const uint2* __restrict__ buckets, const unsigned* __restrict__ cursor,
          const uint4* __restrict__ ovrec, const unsigned* __restrict__ ocur,
          const float2* __restrict__ P2, float* __restrict__ rep,
          unsigned* __restrict__ done, float* __restrict__ out,
          unsigned cap, unsigned ocap, int n_nodes) {
    __shared__ float  acc[AREP][B2SIZE + 8];
    __shared__ float2 p2loc[B2SIZE];
    __shared__ unsigned lastflag;
    const int b   = blockIdx.x >> 4;             // ESLICES == 16
    const int sl  = blockIdx.x & (ESLICES - 1);
    const int tid = threadIdx.x;
    const int rp  = (tid >> 6) & (AREP - 1);

    for (int i = tid; i < AREP * (B2SIZE + 8); i += BLK) acc[0][i] = 0.0f;
    for (int i = tid; i < B2SIZE; i += BLK) {
        int node = (b << B2SHIFT) + i;
        p2loc[i] = (node < n_nodes) ? P2[node] : make_float2(0.f, 0.f);
    }
    __syncthreads();

    unsigned count = cursor[b];
    if (count > cap) count = cap;
    unsigned seg = (((count + ESLICES - 1) / ESLICES) + 3u) & ~3u;   // 4-rec aligned
    unsigned st  = (unsigned)sl * seg; if (st > count) st = count;
    unsigned en  = st + seg; if (en > count) en = count;

    const uint2* src = buckets + (size_t)b * cap;
    for (unsigned i = st + tid * 4; i < en; i += BLK * 4) {
        if (i + 4 <= en) {
            uint4 q0 = *(const uint4*)(src + i);
            uint4 q1 = *(const uint4*)(src + i + 2);
            unsigned sx[4] = {q0.x, q0.z, q1.x, q1.z};
            unsigned lb[4] = {q0.y, q0.w, q1.y, q1.w};
            float2 ps[4];
            #pragma unroll
            for (int j = 0; j < 4; ++j) ps[j] = P2[sx[j] & 0x1FFFFu];
            #pragma unroll
            for (int j = 0; j < 4; ++j) {
                unsigned rlow = (sx[j] >> 17) & (B2SIZE - 1);
                float e = gnb_energy_eval(ps[j], p2loc[rlow], __uint_as_float(lb[j]));
                atomicAdd(&acc[rp][rlow], e);
            }
        } else {
            for (unsigned q = i; q < en; ++q) {
                uint2 rec = src[q];
                unsigned rlow = (rec.x >> 17) & (B2SIZE - 1);
                float e = gnb_energy_eval(P2[rec.x & 0x1FFFFu], p2loc[rlow],
                                          __uint_as_float(rec.y));
                atomicAdd(&acc[rp][rlow], e);
            }
        }
    }

    if (sl == 0) {                    // overflow fold (usually empty)
        unsigned n = *ocur; if (n > ocap) n = ocap;
        for (unsigned i = tid; i < n; i += BLK) {
            uint4 rc = ovrec[i];
            if ((rc.x >> B2SHIFT) == (unsigned)b) {
                float e = gnb_energy_eval(P2[rc.y], p2loc[rc.x & (B2SIZE - 1)],
                                          __uint_as_float(rc.z));
                atomicAdd(&acc[rp][rc.x & (B2SIZE - 1)], e);
            }
        }
    }
    __syncthreads();

    float* dst = rep + (size_t)blockIdx.x * B2SIZE;
    for (int i = tid; i < B2SIZE; i += BLK)
        dst[i] = acc[0][i] + acc[1][i];

    // last-block reduce (G16: device fence + device-scope atomic)
    __threadfence();
    if (tid == 0) lastflag = atomicAdd(&done[b], 1u);
    __syncthreads();
    if (lastflag == ESLICES - 1) {
        __threadfence();
        const float* srcr = rep + ((size_t)b * ESLICES) * B2SIZE;
        for (int i = tid; i < B2SIZE; i += BLK) {
            int node = (b << B2SHIFT) + i;
            if (node < n_nodes) {
                float s = 0.0f;
                #pragma unroll
                for (int k = 0; k < ESLICES; ++k)
                    s += srcr[(size_t)k * B2SIZE + i];
                out[node] = s;
            }
        }
    }
}

extern "C" void kernel_launch(void* const* d_in, const int* in_sizes, int n_in,
                              void* d_out, int out_size, void* d_ws, size_t ws_size,
                              hipStream_t stream) {
    const int*   Z    = (const int*)d_in[0];
    const int*   eidx = (const int*)d_in[1];
    const float* len  = (const float*)d_in[2];
    float*       out  = (float*)d_out;

    const int n_nodes = in_sizes[0];
    const int n_edges = in_sizes[2];
    const int* send = eidx;
    const int* recv = eidx + n_edges;

    const int NB2 = (n_nodes + B2SIZE - 1) >> B2SHIFT;   // 98 for n=100000
    const int nw  = (n_nodes + 31) >> 5;
    const int nwp = (nw + 7) & ~7;
    const int cnw = (n_nodes + 3) & ~3;                  // cn slot, 16B-aligned

    // ws layout (words): [cursor 128][done 128][cntrs 8][cn cnw][P2 2n][isCN nwp]
    //                    [rep][ovrec][buckets]
    char* ws = (char*)d_ws;
    unsigned* cursor = (unsigned*)ws;                                            // 128
    unsigned* done   = (unsigned*)(ws + MAXB * 4);                               // 128
    unsigned* cntrs  = (unsigned*)(ws + 2 * MAXB * 4);                           // 8
    int*      cn     = (int*)(ws + (2 * MAXB + 8) * 4);                          // cnw
    float2*   P2     = (float2*)(ws + ((size_t)cnw + 2 * MAXB + 8) * 4);         // 2n
    unsigned* isCN   = (unsigned*)(ws + ((size_t)cnw + 2 * (size_t)n_nodes
                                         + 2 * MAXB + 8) * 4);                   // nwp
    float*    rep    = (float*)((char*)isCN + (size_t)nwp * 4);
    size_t rep_w     = (size_t)NB2 * ESLICES * B2SIZE;
    char*     tail   = (char*)rep + rep_w * 4;

    size_t fixed_words = (size_t)cnw + 2 * (size_t)n_nodes + 2 * MAXB + 8
                         + nwp + rep_w;
    size_t total_words = ws_size / 4;
    size_t avail = total_words > fixed_words ? total_words - fixed_words : 0;
    size_t ovw = avail / 64;                      // ~1.5% to overflow queue
    unsigned ocap = (unsigned)(ovw / 4);          // uint4 records
    size_t capw = (avail - ovw) / (size_t)NB2;    // words per bucket
    long cap = (long)((capw / 2) & ~(size_t)3);   // uint2 records, 4-rec aligned
    if (cap > n_edges) cap = (n_edges + 3) & ~3;
    if (cap < 0) cap = 0;
    uint4* ovrec   = (uint4*)tail;
    uint2* buckets = (uint2*)(tail + (size_t)ocap * 16);

    const int B = 256;
    int node_blocks = (n_nodes + B - 1) / B;
    int scat_blocks = (n_edges + TILE - 1) / TILE;
    int nunits      = NB2 * ESLICES;
    int zero_words  = cnw + 2 * MAXB + 8;         // cursor + done + cntrs + cn
    int zq = zero_words / 4;

    gnb_init<<<256, B, 0, stream>>>(Z, isCN, nw, n_nodes, (int4*)ws, zq,
                                    (int*)ws, zero_words);
    gnb_scatter<<<scat_blocks, SBLK, 0, stream>>>(send, recv, len, isCN, cn,
                                                  buckets, cursor, ovrec, cntrs,
                                                  n_edges, (unsigned)cap, ocap);
    gnb_params<<<node_blocks, B, 0, stream>>>(Z, cn, P2, n_nodes);
    gnb_accum<<<nunits, BLK, 0, stream>>>(buckets, cursor, ovrec, cntrs,
                                          P2, rep, done, out,
                                          (unsigned)cap, ocap, n_nodes);
}

// Round 12
// 195.700 us; speedup vs baseline: 2.4362x; 1.9671x over previous
//
#include <hip/hip_runtime.h>

// GNB dispersion — Round 19: R16 pipeline + high-TLP accum (fence fold reverted).
// R18 lesson (joins R17's): on 8-XCD MI355X any device-scope visibility op
// (grid.sync ~150us; per-block __threadfence ~L2-writeback x1568 -> accum 260us)
// dwarfs a ~14us kernel launch. Kernel boundaries ARE the cheap fence.
// vs R16: accum ESLICES 8->16, AREP 4->2 (LDS 16.5KB -> ~8 blocks/CU, 32 waves)
// to hide the 6M P2[s] gather latency (records are L3-resident: R18 FETCH 30MB).
//   init -> scatter(+degree) -> params -> accum -> reduce
// Record: uint2{ s | rlow<<17, len_bits }.
// ws (words): [cursor 128][cntrs 8][cn cnw][P2 2n][isCN nwp]
//             [rep NB2*ES*1024][ovrec uint4 ocap][buckets uint2 NB2*cap]

#define B2SHIFT 10
#define B2SIZE  1024
#define TILE    4096
#define SBLK    512
#define ESLICES 16
#define MAXB    128
#define AREP    2
#define BLK     256

__device__ __constant__ float2 GNB_RC6[87] = {
    {0.f, 0.f},
    {3.6516f, 95.99f},   {2.1843f, 40.67f},   {1.2711f, 70.21f},
    {3.3497f, 114.51f},  {2.7079f, 152.36f},  {1.8219f, 184.28f},
    {2.4667f, 482.54f},  {2.365f, 405.57f},   {1.5062f, 218.45f},
    {1.8233f, 174.81f},  {1.3974f, 181.7f},   {3.3515f, 263.02f},
    {3.0102f, 228.1f},   {3.1629f, 359.43f},  {3.2554f, 3222.12f},
    {2.9539f, 2144.49f}, {3.0368f, 2072.46f}, {2.6598f, 1357.42f},
    {4.0877f, 1406.65f}, {4.1275f, 1058.36f}, {9.7282f, 11498.73f},
    {8.5322f, 3361.33f}, {7.2344f, 2095.91f}, {5.3605f, 1049.31f},
    {3.718f, 966.27f},   {3.6408f, 1571.36f}, {3.4961f, 1183.59f},
    {3.5108f, 787.76f},  {3.0537f, 563.93f},  {3.0261f, 592.91f},
    {3.1735f, 430.82f},  {3.1773f, 812.57f},  {3.8357f, 4533.53f},
    {3.1109f, 3440.92f}, {3.2122f, 3859.82f}, {2.8263f, 2729.6f},
    {2.412f, 1864.19f},  {1.894f, 1175.73f},  {11.2061f, 32141.18f},
    {6.821f, 27655.14f}, {7.2367f, 2864.2f},  {3.901f, 3563.45f},
    {4.0857f, 3266.43f}, {4.045f, 3967.23f},  {3.4813f, 2233.82f},
    {3.0487f, 1393.49f}, {2.7795f, 1315.09f}, {2.8673f, 1311.47f},
    {3.3339f, 1460.56f}, {3.0086f, 1662.99f}, {3.9919f, 8089.97f},
    {3.4209f, 6887.05f}, {3.5649f, 8799.32f}, {3.0288f, 6136.5f},
    {2.262f, 3757.31f},  {1.3837f, 2561.18f}, {12.171f, 66580.83f},
    {0.f,0.f},{0.f,0.f},{0.f,0.f},{0.f,0.f},{0.f,0.f},{0.f,0.f},{0.f,0.f},
    {0.f,0.f},{0.f,0.f},{0.f,0.f},{0.f,0.f},{0.f,0.f},{0.f,0.f},{0.f,0.f},
    {6.0791f, 27593.76f}, {5.7661f, 15364.65f}, {3.6366f, 2734.5f},
    {4.241f, 4801.82f},   {4.1348f, 5685.94f},  {3.4213f, 2786.0f},
    {3.2486f, 2699.79f},  {2.9588f, 2282.6f},   {2.9381f, 2476.79f},
    {2.7711f, 2988.7f},   {2.5816f, 2506.63f},  {3.785f, 8916.84f},
    {3.5381f, 8694.22f},  {3.6985f, 11821.61f}, {3.0551f, 8410.64f},
};

// Zero [cursor|cntrs|cn] (contiguous at ws start) + build isCN bitmask.
__global__ void gnb_init(const int* __restrict__ Z, unsigned* __restrict__ isCN,
                         int nw, int n_nodes, int4* __restrict__ zp4, int zq,
                         int* __restrict__ zp, int zwords) {
    int stride = gridDim.x * blockDim.x;
    int t0 = blockIdx.x * blockDim.x + threadIdx.x;
    int4 z4 = make_int4(0, 0, 0, 0);
    for (int i = t0; i < zq; i += stride) zp4[i] = z4;
    for (int i = zq * 4 + t0; i < zwords; i += stride) zp[i] = 0;
    for (int w = t0; w < nw; w += stride) {
        unsigned m = 0;
        int base = w << 5;
        int lim = n_nodes - base; if (lim > 32) lim = 32;
        for (int k = 0; k < lim; ++k) {
            int z = Z[base + k];
            if (z == 6 || z == 7) m |= (1u << k);
        }
        isCN[w] = m;
    }
}

__global__ void gnb_params(const int* __restrict__ Z, const int* __restrict__ cn,
                           float2* __restrict__ P2, int n_nodes) {
    int i = blockIdx.x * blockDim.x + threadIdx.x;
    if (i >= n_nodes) return;
    int z = Z[i];
    float Rp, C6;
    if (z == 6) {
        if (cn[i] <= 3) { Rp = 2.2348f; C6 = 429.69f; }
        else            { Rp = 1.8219f; C6 = 184.28f; }
    } else if (z == 7) {
        if (cn[i] <= 2) { Rp = 2.6454f; C6 = 720.18f; }
        else            { Rp = 2.4667f; C6 = 482.54f; }
    } else {
        float2 rc = GNB_RC6[z];
        Rp = rc.x; C6 = rc.y;
    }
    P2[i] = make_float2(sqrtf(C6), sqrtf(sqrtf(Rp)));
}

__device__ __forceinline__ float gnb_energy_eval(float2 ps, float2 pr, float rlen) {
    float env;
    if (rlen < 8.0f) {
        env = 1.0f;
    } else {
        float x = (rlen - 8.0f) * 0.5f;          // kept edges guarantee x < 1
        float x2 = x * x;
        float x6 = x2 * x2 * x2;
        env = 1.0f - 28.0f * x6 + 48.0f * x6 * x - 21.0f * x6 * x2;
    }
    float sR  = ps.y * pr.y;                     // sqrt(R_ij)
    float C6  = ps.x * pr.x;                     // sqrt(C6_s*C6_r)
    float Rij = sR * sR;
    float R3  = Rij * Rij * Rij;
    float R6  = R3 * R3;
    float r0  = 0.4f * sR + 4.0f;
    float t   = r0 / rlen;
    float t2 = t * t, t4 = t2 * t2, t8 = t4 * t4;
    float t14 = t8 * t4 * t2;
    float fd = 1.0f / (1.0f + 6.0f * t14);
    float rl2 = rlen * rlen;
    float r6 = rl2 * rl2 * rl2;
    return -0.5f * C6 / (R6 + r6) * fd * env;
}

// Gather-free scatter (+fused degree): identical to R16 (62us proven).
__global__ void __launch_bounds__(SBLK)
gnb_scatter(const int* __restrict__ send, const int* __restrict__ recv,
            const float* __restrict__ len, const unsigned* __restrict__ isCN,
            int* __restrict__ cn,
            uint2* __restrict__ buckets, unsigned* __restrict__ cursor,
            uint4* __restrict__ ovrec, unsigned* __restrict__ ocur,
            int n_edges, unsigned cap, unsigned ocap) {
    __shared__ unsigned hist[MAXB];
    __shared__ unsigned gbase[MAXB];
    const int tid = threadIdx.x;
    const int e0  = blockIdx.x * TILE;

    if (tid < MAXB) hist[tid] = 0;
    __syncthreads();

    unsigned ss[8]; unsigned rr[8]; float ll[8];
    const bool full = (e0 + TILE <= n_edges);
    if (full) {
        int4   sv0 = *(const int4*)(send + e0 + tid * 4);
        int4   rv0 = *(const int4*)(recv + e0 + tid * 4);
        float4 lv0 = *(const float4*)(len + e0 + tid * 4);
        int4   sv1 = *(const int4*)(send + e0 + 2048 + tid * 4);
        int4   rv1 = *(const int4*)(recv + e0 + 2048 + tid * 4);
        float4 lv1 = *(const float4*)(len + e0 + 2048 + tid * 4);
        ss[0]=(unsigned)sv0.x; ss[1]=(unsigned)sv0.y; ss[2]=(unsigned)sv0.z; ss[3]=(unsigned)sv0.w;
        ss[4]=(unsigned)sv1.x; ss[5]=(unsigned)sv1.y; ss[6]=(unsigned)sv1.z; ss[7]=(unsigned)sv1.w;
        rr[0]=(unsigned)rv0.x; rr[1]=(unsigned)rv0.y; rr[2]=(unsigned)rv0.z; rr[3]=(unsigned)rv0.w;
        rr[4]=(unsigned)rv1.x; rr[5]=(unsigned)rv1.y; rr[6]=(unsigned)rv1.z; rr[7]=(unsigned)rv1.w;
        ll[0]=lv0.x; ll[1]=lv0.y; ll[2]=lv0.z; ll[3]=lv0.w;
        ll[4]=lv1.x; ll[5]=lv1.y; ll[6]=lv1.z; ll[7]=lv1.w;
    } else {
        #pragma unroll
        for (int i = 0; i < 8; ++i) {
            int e = e0 + ((i >> 2) * 2048) + tid * 4 + (i & 3);
            bool ok = (e < n_edges);
            ss[i] = ok ? (unsigned)send[e] : 0u;
            rr[i] = ok ? (unsigned)recv[e] : 0u;
            ll[i] = ok ? len[e] : 1.0e9f;
        }
    }

    // fused degree: ALL edges, isCN-filtered (~2.3% fire), fire-and-forget
    #pragma unroll
    for (int i = 0; i < 8; ++i) {
        if (ll[i] < 1.0e8f && ((isCN[rr[i] >> 5] >> (rr[i] & 31)) & 1u))
            atomicAdd(&cn[rr[i]], 1);
    }

    unsigned bk[8];
    #pragma unroll
    for (int i = 0; i < 8; ++i) {
        if (ll[i] < 10.0f) {
            unsigned b   = rr[i] >> B2SHIFT;
            unsigned off = atomicAdd(&hist[b], 1u);
            bk[i] = b | (off << 7);
        } else {
            bk[i] = 0x80000000u;
        }
    }
    __syncthreads();

    if (tid < MAXB) {
        unsigned c = hist[tid];
        gbase[tid] = c ? atomicAdd(&cursor[tid], c) : 0u;
    }
    __syncthreads();

    #pragma unroll
    for (int i = 0; i < 8; ++i) {
        unsigned bo = bk[i];
        if (!(bo & 0x80000000u)) {
            unsigned b = bo & (MAXB - 1);
            unsigned g = gbase[b] + (bo >> 7);
            unsigned x = ss[i] | ((rr[i] & (B2SIZE - 1)) << 17);
            if (g < cap) {
                buckets[(size_t)b * cap + g] = make_uint2(x, __float_as_uint(ll[i]));
            } else {
                unsigned o = atomicAdd(ocur, 1u);
                if (o < ocap)
                    ovrec[o] = make_uint4(rr[i], ss[i], __float_as_uint(ll[i]), 0u);
            }
        }
    }
}

// Accum: stage bucket P2 in LDS, stream records, gather P2[s], eval, LDS add
// (2 replicas). No fence, no cross-block protocol — reduce is a separate kernel.
__global__ void __launch_bounds__(BLK)
gnb_accum(const uint2* __restrict__ buckets, const unsigned* __restrict__ cursor,
          const uint4* __restrict__ ovrec, const unsigned* __restrict__ ocur,
          const float2* __restrict__ P2, float* __restrict__ rep,
          unsigned cap, unsigned ocap, int n_nodes) {
    __shared__ float  acc[AREP][B2SIZE + 8];
    __shared__ float2 p2loc[B2SIZE];
    const int b   = blockIdx.x >> 4;             // ESLICES == 16
    const int sl  = blockIdx.x & (ESLICES - 1);
    const int tid = threadIdx.x;
    const int rp  = (tid >> 6) & (AREP - 1);

    for (int i = tid; i < AREP * (B2SIZE + 8); i += BLK) acc[0][i] = 0.0f;
    for (int i = tid; i < B2SIZE; i += BLK) {
        int node = (b << B2SHIFT) + i;
        p2loc[i] = (node < n_nodes) ? P2[node] : make_float2(0.f, 0.f);
    }
    __syncthreads();

    if (sl == 0) {                    // overflow fold first (usually empty)
        unsigned n = *ocur; if (n > ocap) n = ocap;
        for (unsigned i = tid; i < n; i += BLK) {
            uint4 rc = ovrec[i];
            if ((rc.x >> B2SHIFT) == (unsigned)b) {
                float e = gnb_energy_eval(P2[rc.y], p2loc[rc.x & (B2SIZE - 1)],
                                          __uint_as_float(rc.z));
                atomicAdd(&acc[rp][rc.x & (B2SIZE - 1)], e);
            }
        }
    }

    unsigned count = cursor[b];
    if (count > cap) count = cap;
    unsigned seg = (((count + ESLICES - 1) / ESLICES) + 3u) & ~3u;   // 4-rec aligned
    unsigned st  = (unsigned)sl * seg; if (st > count) st = count;
    unsigned en  = st + seg; if (en > count) en = count;

    const uint2* src = buckets + (size_t)b * cap;
    for (unsigned i = st + tid * 4; i < en; i += BLK * 4) {
        if (i + 4 <= en) {
            uint4 q0 = *(const uint4*)(src + i);
            uint4 q1 = *(const uint4*)(src + i + 2);
            unsigned sx[4] = {q0.x, q0.z, q1.x, q1.z};
            unsigned lb[4] = {q0.y, q0.w, q1.y, q1.w};
            float2 ps[4];
            #pragma unroll
            for (int j = 0; j < 4; ++j) ps[j] = P2[sx[j] & 0x1FFFFu];
            #pragma unroll
            for (int j = 0; j < 4; ++j) {
                unsigned rlow = (sx[j] >> 17) & (B2SIZE - 1);
                float e = gnb_energy_eval(ps[j], p2loc[rlow], __uint_as_float(lb[j]));
                atomicAdd(&acc[rp][rlow], e);
            }
        } else {
            for (unsigned q = i; q < en; ++q) {
                uint2 rec = src[q];
                unsigned rlow = (rec.x >> 17) & (B2SIZE - 1);
                float e = gnb_energy_eval(P2[rec.x & 0x1FFFFu], p2loc[rlow],
                                          __uint_as_float(rec.y));
                atomicAdd(&acc[rp][rlow], e);
            }
        }
    }
    __syncthreads();

    float* dst = rep + (size_t)blockIdx.x * B2SIZE;
    for (int i = tid; i < B2SIZE; i += BLK)
        dst[i] = acc[0][i] + acc[1][i];
}

__global__ void gnb_reduce(const float* __restrict__ rep, float* __restrict__ out,
                           int n_nodes) {
    int i = blockIdx.x * blockDim.x + threadIdx.x;
    if (i >= n_nodes) return;
    int b = i >> B2SHIFT;
    int j = i & (B2SIZE - 1);
    const float* src = rep + ((size_t)b * ESLICES) * B2SIZE + j;
    float sum = 0.0f;
    #pragma unroll
    for (int s = 0; s < ESLICES; ++s) sum += src[(size_t)s * B2SIZE];
    out[i] = sum;
}

extern "C" void kernel_launch(void* const* d_in, const int* in_sizes, int n_in,
                              void* d_out, int out_size, void* d_ws, size_t ws_size,
                              hipStream_t stream) {
    const int*   Z    = (const int*)d_in[0];
    const int*   eidx = (const int*)d_in[1];
    const float* len  = (const float*)d_in[2];
    float*       out  = (float*)d_out;

    const int n_nodes = in_sizes[0];
    const int n_edges = in_sizes[2];
    const int* send = eidx;
    const int* recv = eidx + n_edges;

    const int NB2 = (n_nodes + B2SIZE - 1) >> B2SHIFT;   // 98 for n=100000
    const int nw  = (n_nodes + 31) >> 5;
    const int nwp = (nw + 7) & ~7;
    const int cnw = (n_nodes + 3) & ~3;                  // cn slot, 16B-aligned

    // ws layout (words): [cursor 128][cntrs 8][cn cnw][P2 2n][isCN nwp][rep][tail]
    char* ws = (char*)d_ws;
    unsigned* cursor = (unsigned*)ws;                                            // 128
    unsigned* cntrs  = (unsigned*)(ws + MAXB * 4);                               // 8
    int*      cn     = (int*)(ws + (MAXB + 8) * 4);                              // cnw
    float2*   P2     = (float2*)(ws + ((size_t)cnw + MAXB + 8) * 4);             // 2n
    unsigned* isCN   = (unsigned*)(ws + ((size_t)cnw + 2 * (size_t)n_nodes
                                         + MAXB + 8) * 4);                       // nwp
    float*    rep    = (float*)((char*)isCN + (size_t)nwp * 4);
    size_t rep_w     = (size_t)NB2 * ESLICES * B2SIZE;
    char*     tail   = (char*)rep + rep_w * 4;

    size_t fixed_words = (size_t)cnw + 2 * (size_t)n_nodes + MAXB + 8
                         + nwp + rep_w;
    size_t total_words = ws_size / 4;
    size_t avail = total_words > fixed_words ? total_words - fixed_words : 0;
    size_t ovw = avail / 64;                      // ~1.5% to overflow queue
    unsigned ocap = (unsigned)(ovw / 4);          // uint4 records
    size_t capw = (avail - ovw) / (size_t)NB2;    // words per bucket
    long cap = (long)((capw / 2) & ~(size_t)3);   // uint2 records, 4-rec aligned
    if (cap > n_edges) cap = (n_edges + 3) & ~3;
    if (cap < 0) cap = 0;
    uint4* ovrec   = (uint4*)tail;
    uint2* buckets = (uint2*)(tail + (size_t)ocap * 16);

    const int B = 256;
    int node_blocks = (n_nodes + B - 1) / B;
    int scat_blocks = (n_edges + TILE - 1) / TILE;
    int nunits      = NB2 * ESLICES;
    int zero_words  = cnw + MAXB + 8;             // cursor + cntrs + cn
    int zq = zero_words / 4;

    gnb_init<<<256, B, 0, stream>>>(Z, isCN, nw, n_nodes, (int4*)ws, zq,
                                    (int*)ws, zero_words);
    gnb_scatter<<<scat_blocks, SBLK, 0, stream>>>(send, recv, len, isCN, cn,
                                                  buckets, cursor, ovrec, cntrs,
                                                  n_edges, (unsigned)cap, ocap);
    gnb_params<<<node_blocks, B, 0, stream>>>(Z, cn, P2, n_nodes);
    gnb_accum<<<nunits, BLK, 0, stream>>>(buckets, cursor, ovrec, cntrs,
                                          P2, rep, (unsigned)cap, ocap, n_nodes);
    gnb_reduce<<<node_blocks, B, 0, stream>>>(rep, out, n_nodes);
}